// Round 12
// baseline (114.678 us; speedup 1.0000x reference)
//
#include <hip/hip_runtime.h>
#include <cstddef>

#define N_NODES 100000
#define N_EDGES 640000
#define D 128

#define SCAN_N (N_NODES + 1)                 // 100001
#define SCAN_B ((SCAN_N + 1023) / 1024)      // 98

// convert: 3.2M float4 chunks = 2500 blocks * 256 thr * 5 chunks (exact)
#define CONV_BLKS 2500
#define T_CONV (CONV_BLKS * 256)             // 640000

// degrank: 640000 edges = 625 blocks * 256 thr * 4 edges (exact); +16 pack blocks
#define DEG_BLKS 625
#define T_DEG (DEG_BLKS * 256)               // 160000
#define DEGRANK_BLKS (DEG_BLKS + 16)

#define FILL_BLKS 1250
#define T_FILL (FILL_BLKS * 256)             // 320000 (2 edges/thread)

typedef __attribute__((ext_vector_type(4))) float f32x4;
typedef __attribute__((ext_vector_type(8))) short bf16x8;

__device__ __forceinline__ unsigned short f2bf(float f) {
    union { float f; unsigned int u; } v; v.f = f;
    unsigned int u = v.u;
    return (unsigned short)((u + 0x7FFFu + ((u >> 16) & 1u)) >> 16);   // RNE
}
__device__ __forceinline__ float bf2f(unsigned short u) {
    union { unsigned int u; float f; } v; v.u = ((unsigned int)u) << 16;
    return v.f;
}

// ---------------------------------------------------------------------------
// 1) convert: x (fp32) -> xb (bf16), 5 strided chunks/thread, lane-contiguous.
//    Nontemporal x loads (single-use stream; keep L2/L3 for xb reuse).
//    Also zeroes A[0..SCAN_N) and the scan flags (graph-replay safe).
// ---------------------------------------------------------------------------
__global__ __launch_bounds__(256) void convert_kernel(
    const float* __restrict__ x, unsigned short* __restrict__ xb,
    int* __restrict__ A, int* __restrict__ flags)
{
    const int tid = blockIdx.x * 256 + threadIdx.x;
    if (tid < SCAN_N) A[tid] = 0;                 // coalesced; runs before degrank
    if (tid < 128) flags[tid] = 0;                // scan lookback flags
#pragma unroll
    for (int k = 0; k < 5; ++k) {
        const size_t c = (size_t)tid + (size_t)k * T_CONV;
        f32x4 v = __builtin_nontemporal_load((const f32x4*)(x + c * 4));
        uint2 p;
        p.x = (unsigned)f2bf(v[0]) | ((unsigned)f2bf(v[1]) << 16);
        p.y = (unsigned)f2bf(v[2]) | ((unsigned)f2bf(v[3]) << 16);
        *(uint2*)(xb + c * 4) = p;
    }
}

// ---------------------------------------------------------------------------
// 2) degrank: blocks [0,625): deg count + rank capture, 4 strided edges/thr;
//             blocks [625,641): weight pack into MFMA B-fragment order.
//    Wtb fragment f=(ct*8+ks)*64+lane holds 8 bf16:
//    B[k=ks*32+(lane>>4)*8+j][n=ct*16+(lane&15)], k<128 -> W, else Wr.
// ---------------------------------------------------------------------------
__global__ __launch_bounds__(256) void degrank_kernel(
    const int* __restrict__ edge_dst,
    const float* __restrict__ W, const float* __restrict__ Wr,
    int* __restrict__ A, int* __restrict__ rank,
    unsigned short* __restrict__ Wtb)
{
    const int b = blockIdx.x;
    const int t = threadIdx.x;
    if (b < DEG_BLKS) {
        const int tid = b * 256 + t;
        const int e0 = tid;
        const int e1 = tid + T_DEG;
        const int e2 = tid + 2 * T_DEG;
        const int e3 = tid + 3 * T_DEG;
        const int d0 = edge_dst[e0];
        const int d1 = edge_dst[e1];
        const int d2 = edge_dst[e2];
        const int d3 = edge_dst[e3];
        const int r0 = atomicAdd(&A[d0], 1);
        const int r1 = atomicAdd(&A[d1], 1);
        const int r2 = atomicAdd(&A[d2], 1);
        const int r3 = atomicAdd(&A[d3], 1);
        rank[e0] = r0;
        rank[e1] = r1;
        rank[e2] = r2;
        rank[e3] = r3;
    } else {
        const int f = (b - DEG_BLKS) * 256 + t;   // 0..4095
        const int l  = f & 63;
        const int ks = (f >> 6) & 7;
        const int ct = f >> 9;
        const int n  = ct * 16 + (l & 15);
        const int kb = ks * 32 + (l >> 4) * 8;
        unsigned short vals[8];
#pragma unroll
        for (int j = 0; j < 8; ++j) {
            const int k = kb + j;
            const float w = (k < 128) ? W[k * 128 + n] : Wr[(k - 128) * 128 + n];
            vals[j] = f2bf(w);
        }
        uint4 pk;
        pk.x = (unsigned)vals[0] | ((unsigned)vals[1] << 16);
        pk.y = (unsigned)vals[2] | ((unsigned)vals[3] << 16);
        pk.z = (unsigned)vals[4] | ((unsigned)vals[5] << 16);
        pk.w = (unsigned)vals[6] | ((unsigned)vals[7] << 16);
        ((uint4*)Wtb)[f] = pk;
    }
}

// ---------------------------------------------------------------------------
// 3) Single-kernel in-place exclusive scan of A[0..SCAN_N), parallel lookback.
//    98 blocks (all co-resident on 256 CUs -> no deadlock). Block b publishes
//    total+1 via device-scope atomicExch; threads t<b spin on flags[t] in
//    parallel, then tree-reduce the prefix.
// ---------------------------------------------------------------------------
__global__ __launch_bounds__(1024) void scan_kernel(
    int* __restrict__ A, int* __restrict__ flags)
{
    __shared__ int sums[1024];
    __shared__ int red[1024];
    const int t = threadIdx.x;
    const int b = blockIdx.x;
    const int gid = b * 1024 + t;
    const int v = (gid < SCAN_N) ? A[gid] : 0;
    sums[t] = v;
    __syncthreads();
    for (int off = 1; off < 1024; off <<= 1) {       // inclusive scan in LDS
        int u = (t >= off) ? sums[t - off] : 0;
        __syncthreads();
        sums[t] += u;
        __syncthreads();
    }
    if (t == 0) atomicExch(&flags[b], sums[1023] + 1);   // publish block total

    int contrib = 0;
    if (t < b) {                                     // parallel lookback
        int f;
        do { f = atomicAdd(&flags[t], 0); } while (f == 0);
        contrib = f - 1;
    }
    red[t] = contrib;
    __syncthreads();
    for (int s = 512; s > 0; s >>= 1) {
        if (t < s) red[t] += red[t + s];
        __syncthreads();
    }
    const int excl = red[0] + sums[t] - v;
    if (gid < SCAN_N) A[gid] = excl;
}

// ---------------------------------------------------------------------------
// 4) Fill CSR: atomic-free (pos = row_start + precomputed rank), 2 edges/thr.
// ---------------------------------------------------------------------------
__global__ __launch_bounds__(256) void fill_kernel(
    const int* __restrict__ edge_src, const int* __restrict__ edge_dst,
    const int* __restrict__ A /*row_start*/, const int* __restrict__ rank,
    int* __restrict__ csr)
{
    const int tid = blockIdx.x * 256 + threadIdx.x;
    const int e0 = tid;
    const int e1 = tid + T_FILL;
    const int d0 = edge_dst[e0];
    const int d1 = edge_dst[e1];
    const int s0 = edge_src[e0];
    const int s1 = edge_src[e1];
    const int r0 = rank[e0];
    const int r1 = rank[e1];
    csr[A[d0] + r0] = s0;
    csr[A[d1] + r1] = s1;
}

// ---------------------------------------------------------------------------
// 5) Gather-mean: quarter-wave (16 lanes x 16B) per node, fp32 register
//    accumulate over bf16 rows, unroll 4/2/1; write mean row as bf16.
// ---------------------------------------------------------------------------
__global__ __launch_bounds__(256) void gather_kernel(
    const unsigned short* __restrict__ xb, const int* __restrict__ A,
    const int* __restrict__ csr, unsigned short* __restrict__ meanb)
{
    const int t = threadIdx.x;
    const int node = blockIdx.x * 16 + (t >> 4);
    const int l = t & 15;                        // owns dims 8l..8l+7
    const int rs = A[node], re = A[node + 1];
    float acc[8] = {0.f, 0.f, 0.f, 0.f, 0.f, 0.f, 0.f, 0.f};
    const unsigned short* xp = xb + (size_t)l * 8;
    int e = rs;
    for (; e + 3 < re; e += 4) {
        const int s0 = csr[e], s1 = csr[e + 1], s2 = csr[e + 2], s3 = csr[e + 3];
        bf16x8 v0 = *(const bf16x8*)(xp + (size_t)s0 * D);
        bf16x8 v1 = *(const bf16x8*)(xp + (size_t)s1 * D);
        bf16x8 v2 = *(const bf16x8*)(xp + (size_t)s2 * D);
        bf16x8 v3 = *(const bf16x8*)(xp + (size_t)s3 * D);
#pragma unroll
        for (int j = 0; j < 8; ++j)
            acc[j] += (bf2f((unsigned short)v0[j]) + bf2f((unsigned short)v1[j]))
                    + (bf2f((unsigned short)v2[j]) + bf2f((unsigned short)v3[j]));
    }
    if (e + 1 < re) {
        const int s0 = csr[e], s1 = csr[e + 1];
        bf16x8 v0 = *(const bf16x8*)(xp + (size_t)s0 * D);
        bf16x8 v1 = *(const bf16x8*)(xp + (size_t)s1 * D);
#pragma unroll
        for (int j = 0; j < 8; ++j)
            acc[j] += bf2f((unsigned short)v0[j]) + bf2f((unsigned short)v1[j]);
        e += 2;
    }
    if (e < re) {
        const int s = csr[e];
        bf16x8 v = *(const bf16x8*)(xp + (size_t)s * D);
#pragma unroll
        for (int j = 0; j < 8; ++j) acc[j] += bf2f((unsigned short)v[j]);
    }
    const float inv = 1.0f / fmaxf((float)(re - rs), 1.0f);
    uint4 pk;
    pk.x = (unsigned)f2bf(acc[0] * inv) | ((unsigned)f2bf(acc[1] * inv) << 16);
    pk.y = (unsigned)f2bf(acc[2] * inv) | ((unsigned)f2bf(acc[3] * inv) << 16);
    pk.z = (unsigned)f2bf(acc[4] * inv) | ((unsigned)f2bf(acc[5] * inv) << 16);
    pk.w = (unsigned)f2bf(acc[6] * inv) | ((unsigned)f2bf(acc[7] * inv) << 16);
    *(uint4*)(meanb + (size_t)node * D + l * 8) = pk;
}

// ---------------------------------------------------------------------------
// 6) MFMA GEMM: out = meanb @ W + xb @ Wr + bias.
//    512 thr (8 waves), 256 rows/block; Wtb staged in 64 KiB LDS.
//    Nontemporal out stores (write-only; keep L2 for meanb/xb streams).
// ---------------------------------------------------------------------------
__global__ __launch_bounds__(512, 4) void gemm_kernel(
    const unsigned short* __restrict__ meanb,
    const unsigned short* __restrict__ xb,
    const unsigned short* __restrict__ Wtb,
    const float* __restrict__ bias,
    float* __restrict__ out)
{
    __shared__ unsigned short Bs[4096 * 8];      // 64 KiB

    const int t = threadIdx.x;
    {
        const uint4* src = (const uint4*)Wtb;
        uint4* dst = (uint4*)Bs;
#pragma unroll
        for (int i = 0; i < 8; ++i) dst[t + i * 512] = src[t + i * 512];
    }

    const int wave = t >> 6;
    const int lane = t & 63;
    const int base = blockIdx.x * 256;
    const int rL0 = wave * 32 + (lane & 15);
    const int rL1 = rL0 + 16;
    const int kO = (lane >> 4) * 8;

    int g0 = base + rL0; if (g0 > N_NODES - 1) g0 = N_NODES - 1;
    int g1 = base + rL1; if (g1 > N_NODES - 1) g1 = N_NODES - 1;
    const unsigned short* mr0 = meanb + (size_t)g0 * D + kO;
    const unsigned short* mr1 = meanb + (size_t)g1 * D + kO;
    const unsigned short* xr0 = xb + (size_t)g0 * D + kO;
    const unsigned short* xr1 = xb + (size_t)g1 * D + kO;

    f32x4 acc0[8], acc1[8];
#pragma unroll
    for (int ct = 0; ct < 8; ++ct) {
        const float bv = bias[ct * 16 + (lane & 15)];
        f32x4 b4 = {bv, bv, bv, bv};
        acc0[ct] = b4;
        acc1[ct] = b4;
    }
    __syncthreads();

    const bf16x8* __restrict__ Bp = (const bf16x8*)Bs;
#pragma unroll
    for (int ks = 0; ks < 4; ++ks) {
        bf16x8 am0 = *(const bf16x8*)(mr0 + ks * 32);
        bf16x8 am1 = *(const bf16x8*)(mr1 + ks * 32);
        bf16x8 ax0 = *(const bf16x8*)(xr0 + ks * 32);
        bf16x8 ax1 = *(const bf16x8*)(xr1 + ks * 32);
#pragma unroll
        for (int ct = 0; ct < 8; ++ct) {
            bf16x8 bm = Bp[(ct * 8 + ks) * 64 + lane];
            bf16x8 bx = Bp[(ct * 8 + 4 + ks) * 64 + lane];
            acc0[ct] = __builtin_amdgcn_mfma_f32_16x16x32_bf16(am0, bm, acc0[ct], 0, 0, 0);
            acc1[ct] = __builtin_amdgcn_mfma_f32_16x16x32_bf16(am1, bm, acc1[ct], 0, 0, 0);
            acc0[ct] = __builtin_amdgcn_mfma_f32_16x16x32_bf16(ax0, bx, acc0[ct], 0, 0, 0);
            acc1[ct] = __builtin_amdgcn_mfma_f32_16x16x32_bf16(ax1, bx, acc1[ct], 0, 0, 0);
        }
    }

    // C/D layout: col = lane&15, row = (lane>>4)*4 + reg
    const int row0b = base + wave * 32 + (lane >> 4) * 4;
#pragma unroll
    for (int ct = 0; ct < 8; ++ct) {
        const int col = ct * 16 + (lane & 15);
#pragma unroll
        for (int r = 0; r < 4; ++r) {
            const int row0 = row0b + r;
            if (row0 < N_NODES)
                __builtin_nontemporal_store(acc0[ct][r], &out[(size_t)row0 * D + col]);
            const int row1 = row0 + 16;
            if (row1 < N_NODES)
                __builtin_nontemporal_store(acc1[ct][r], &out[(size_t)row1 * D + col]);
        }
    }
}

extern "C" void kernel_launch(void* const* d_in, const int* in_sizes, int n_in,
                              void* d_out, int out_size, void* d_ws, size_t ws_size,
                              hipStream_t stream) {
    const float* x           = (const float*)d_in[0];
    const float* weight      = (const float*)d_in[1];
    const float* root_weight = (const float*)d_in[2];
    const float* bias        = (const float*)d_in[3];
    const int* edge_src      = (const int*)d_in[4];
    const int* edge_dst      = (const int*)d_in[5];
    float* out = (float*)d_out;

    // ws layout:
    //   xb       bf16[N][128]        25,600,000 B
    //   meanb    bf16[N][128]        25,600,000 B
    //   Wtb      bf16[4096*8]            65,536 B
    //   A        int[100001]  (deg -> row_start in-place)
    //   rank     int[640000]
    //   flags    int[128]     (scan lookback; zeroed by convert each call)
    //   csr      int[640000]
    char* wsb = (char*)d_ws;
    unsigned short* xb    = (unsigned short*)wsb;
    unsigned short* meanb = (unsigned short*)(wsb + 25600000);
    unsigned short* Wtb   = (unsigned short*)(wsb + 51200000);
    int* A     = (int*)(wsb + 51265536);
    int* rank  = A + SCAN_N;
    int* flags = rank + N_EDGES;
    int* csr   = flags + 128;

    convert_kernel<<<CONV_BLKS, 256, 0, stream>>>(x, xb, A, flags);
    degrank_kernel<<<DEGRANK_BLKS, 256, 0, stream>>>(
        edge_dst, weight, root_weight, A, rank, Wtb);
    scan_kernel<<<SCAN_B, 1024, 0, stream>>>(A, flags);
    fill_kernel<<<FILL_BLKS, 256, 0, stream>>>(
        edge_src, edge_dst, A, rank, csr);

    gather_kernel<<<N_NODES / 16, 256, 0, stream>>>(xb, A, csr, meanb);

    const int gemm_blocks = (N_NODES + 255) / 256;   // 391
    gemm_kernel<<<gemm_blocks, 512, 0, stream>>>(meanb, xb, Wtb, bias, out);
}

// Round 13
// 110.464 us; speedup vs baseline: 1.0381x; 1.0381x over previous
//
#include <hip/hip_runtime.h>
#include <cstddef>

#define N_NODES 100000
#define N_EDGES 640000
#define D 128

#define SCAN_N (N_NODES + 1)                 // 100001
#define SCAN_B ((SCAN_N + 1023) / 1024)      // 98

// convert: 3.2M float4 chunks = 2500 blocks * 256 thr * 5 chunks (exact)
#define CONV_BLKS 2500
#define T_CONV (CONV_BLKS * 256)             // 640000

// degrank: 640000 edges = 625 blocks * 256 thr * 4 edges (exact); +16 pack blocks
#define DEG_BLKS 625
#define T_DEG (DEG_BLKS * 256)               // 160000
#define DEGRANK_BLKS (DEG_BLKS + 16)

#define FILL_BLKS 1250
#define T_FILL (FILL_BLKS * 256)             // 320000 (2 edges/thread)

typedef __attribute__((ext_vector_type(4))) float f32x4;
typedef __attribute__((ext_vector_type(8))) short bf16x8;

__device__ __forceinline__ unsigned short f2bf(float f) {
    union { float f; unsigned int u; } v; v.f = f;
    unsigned int u = v.u;
    return (unsigned short)((u + 0x7FFFu + ((u >> 16) & 1u)) >> 16);   // RNE
}
__device__ __forceinline__ float bf2f(unsigned short u) {
    union { unsigned int u; float f; } v; v.u = ((unsigned int)u) << 16;
    return v.f;
}

// ---------------------------------------------------------------------------
// 1) convert: x (fp32) -> xb (bf16), 5 strided chunks/thread, lane-contiguous.
//    Also zeroes A[0..SCAN_N) (replaces the slow runtime fillBuffer dispatch).
// ---------------------------------------------------------------------------
__global__ __launch_bounds__(256) void convert_kernel(
    const float* __restrict__ x, unsigned short* __restrict__ xb,
    int* __restrict__ A)
{
    const int tid = blockIdx.x * 256 + threadIdx.x;
    if (tid < SCAN_N) A[tid] = 0;                 // coalesced; runs before degrank
#pragma unroll
    for (int k = 0; k < 5; ++k) {
        const size_t c = (size_t)tid + (size_t)k * T_CONV;
        f32x4 v = *(const f32x4*)(x + c * 4);
        uint2 p;
        p.x = (unsigned)f2bf(v[0]) | ((unsigned)f2bf(v[1]) << 16);
        p.y = (unsigned)f2bf(v[2]) | ((unsigned)f2bf(v[3]) << 16);
        *(uint2*)(xb + c * 4) = p;
    }
}

// ---------------------------------------------------------------------------
// 2) degrank: blocks [0,625): deg count + rank capture, 4 strided edges/thr;
//             blocks [625,641): weight pack into MFMA B-fragment order.
//    Wtb fragment f=(ct*8+ks)*64+lane holds 8 bf16:
//    B[k=ks*32+(lane>>4)*8+j][n=ct*16+(lane&15)], k<128 -> W, else Wr.
// ---------------------------------------------------------------------------
__global__ __launch_bounds__(256) void degrank_kernel(
    const int* __restrict__ edge_dst,
    const float* __restrict__ W, const float* __restrict__ Wr,
    int* __restrict__ A, int* __restrict__ rank,
    unsigned short* __restrict__ Wtb)
{
    const int b = blockIdx.x;
    const int t = threadIdx.x;
    if (b < DEG_BLKS) {
        const int tid = b * 256 + t;
        const int e0 = tid;
        const int e1 = tid + T_DEG;
        const int e2 = tid + 2 * T_DEG;
        const int e3 = tid + 3 * T_DEG;
        const int d0 = edge_dst[e0];
        const int d1 = edge_dst[e1];
        const int d2 = edge_dst[e2];
        const int d3 = edge_dst[e3];
        const int r0 = atomicAdd(&A[d0], 1);
        const int r1 = atomicAdd(&A[d1], 1);
        const int r2 = atomicAdd(&A[d2], 1);
        const int r3 = atomicAdd(&A[d3], 1);
        rank[e0] = r0;
        rank[e1] = r1;
        rank[e2] = r2;
        rank[e3] = r3;
    } else {
        const int f = (b - DEG_BLKS) * 256 + t;   // 0..4095
        const int l  = f & 63;
        const int ks = (f >> 6) & 7;
        const int ct = f >> 9;
        const int n  = ct * 16 + (l & 15);
        const int kb = ks * 32 + (l >> 4) * 8;
        unsigned short vals[8];
#pragma unroll
        for (int j = 0; j < 8; ++j) {
            const int k = kb + j;
            const float w = (k < 128) ? W[k * 128 + n] : Wr[(k - 128) * 128 + n];
            vals[j] = f2bf(w);
        }
        uint4 pk;
        pk.x = (unsigned)vals[0] | ((unsigned)vals[1] << 16);
        pk.y = (unsigned)vals[2] | ((unsigned)vals[3] << 16);
        pk.z = (unsigned)vals[4] | ((unsigned)vals[5] << 16);
        pk.w = (unsigned)vals[6] | ((unsigned)vals[7] << 16);
        ((uint4*)Wtb)[f] = pk;
    }
}

// ---------------------------------------------------------------------------
// 3a) Per-block partial sums of A[0..SCAN_N).
// ---------------------------------------------------------------------------
__global__ __launch_bounds__(1024) void scan_part_kernel(
    const int* __restrict__ A, int* __restrict__ partials)
{
    __shared__ int red[1024];
    const int t = threadIdx.x;
    const int gid = blockIdx.x * 1024 + t;
    red[t] = (gid < SCAN_N) ? A[gid] : 0;
    __syncthreads();
    for (int s = 512; s > 0; s >>= 1) {
        if (t < s) red[t] += red[t + s];
        __syncthreads();
    }
    if (t == 0) partials[blockIdx.x] = red[0];
}

// ---------------------------------------------------------------------------
// 3b) In-place exclusive scan; each block derives its offset from partials.
// ---------------------------------------------------------------------------
__global__ __launch_bounds__(1024) void scan_apply_kernel(
    int* __restrict__ A, const int* __restrict__ partials)
{
    __shared__ int ps[128];
    __shared__ int sums[1024];
    const int t = threadIdx.x;
    if (t < 128) ps[t] = (t < SCAN_B) ? partials[t] : 0;
    __syncthreads();
    for (int off = 1; off < 128; off <<= 1) {
        int v = (t < 128 && t >= off) ? ps[t - off] : 0;
        __syncthreads();
        if (t < 128) ps[t] += v;
        __syncthreads();
    }
    const int block_off = (blockIdx.x == 0) ? 0 : ps[blockIdx.x - 1];

    const int gid = blockIdx.x * 1024 + t;
    const int v = (gid < SCAN_N) ? A[gid] : 0;
    sums[t] = v;
    __syncthreads();
    for (int off = 1; off < 1024; off <<= 1) {
        int u = (t >= off) ? sums[t - off] : 0;
        __syncthreads();
        sums[t] += u;
        __syncthreads();
    }
    if (gid < SCAN_N) A[gid] = block_off + (sums[t] - v);
}

// ---------------------------------------------------------------------------
// 4) Fill CSR: atomic-free (pos = row_start + precomputed rank), 2 edges/thr.
// ---------------------------------------------------------------------------
__global__ __launch_bounds__(256) void fill_kernel(
    const int* __restrict__ edge_src, const int* __restrict__ edge_dst,
    const int* __restrict__ A /*row_start*/, const int* __restrict__ rank,
    int* __restrict__ csr)
{
    const int tid = blockIdx.x * 256 + threadIdx.x;
    const int e0 = tid;
    const int e1 = tid + T_FILL;
    const int d0 = edge_dst[e0];
    const int d1 = edge_dst[e1];
    const int s0 = edge_src[e0];
    const int s1 = edge_src[e1];
    const int r0 = rank[e0];
    const int r1 = rank[e1];
    csr[A[d0] + r0] = s0;
    csr[A[d1] + r1] = s1;
}

// ---------------------------------------------------------------------------
// 5) Gather-mean: quarter-wave (16 lanes x 16B) per node, fp32 register
//    accumulate over bf16 rows. 8-deep chunked loads: 8 independent row
//    loads issued back-to-back (needs ~60 VGPR -> launch_bounds(256,4)
//    so the allocator doesn't serialize them like the old 12-VGPR build).
// ---------------------------------------------------------------------------
__global__ __launch_bounds__(256, 4) void gather_kernel(
    const unsigned short* __restrict__ xb, const int* __restrict__ A,
    const int* __restrict__ csr, unsigned short* __restrict__ meanb)
{
    const int t = threadIdx.x;
    const int node = blockIdx.x * 16 + (t >> 4);
    const int l = t & 15;                        // owns dims 8l..8l+7
    const int rs = A[node], re = A[node + 1];
    float acc[8] = {0.f, 0.f, 0.f, 0.f, 0.f, 0.f, 0.f, 0.f};
    const unsigned short* xp = xb + (size_t)l * 8;
    int e = rs;
    for (; e + 7 < re; e += 8) {                 // 8 loads in flight
        bf16x8 v[8];
#pragma unroll
        for (int j = 0; j < 8; ++j) {
            const int s = csr[e + j];
            v[j] = *(const bf16x8*)(xp + (size_t)s * D);
        }
#pragma unroll
        for (int j = 0; j < 8; ++j)
#pragma unroll
            for (int k = 0; k < 8; ++k) acc[k] += bf2f((unsigned short)v[j][k]);
    }
    for (; e + 3 < re; e += 4) {                 // 4 in flight
        bf16x8 v[4];
#pragma unroll
        for (int j = 0; j < 4; ++j) {
            const int s = csr[e + j];
            v[j] = *(const bf16x8*)(xp + (size_t)s * D);
        }
#pragma unroll
        for (int j = 0; j < 4; ++j)
#pragma unroll
            for (int k = 0; k < 8; ++k) acc[k] += bf2f((unsigned short)v[j][k]);
    }
    if (e + 1 < re) {
        const int s0 = csr[e], s1 = csr[e + 1];
        bf16x8 v0 = *(const bf16x8*)(xp + (size_t)s0 * D);
        bf16x8 v1 = *(const bf16x8*)(xp + (size_t)s1 * D);
#pragma unroll
        for (int k = 0; k < 8; ++k)
            acc[k] += bf2f((unsigned short)v0[k]) + bf2f((unsigned short)v1[k]);
        e += 2;
    }
    if (e < re) {
        const int s = csr[e];
        bf16x8 v = *(const bf16x8*)(xp + (size_t)s * D);
#pragma unroll
        for (int k = 0; k < 8; ++k) acc[k] += bf2f((unsigned short)v[k]);
    }
    const float inv = 1.0f / fmaxf((float)(re - rs), 1.0f);
    uint4 pk;
    pk.x = (unsigned)f2bf(acc[0] * inv) | ((unsigned)f2bf(acc[1] * inv) << 16);
    pk.y = (unsigned)f2bf(acc[2] * inv) | ((unsigned)f2bf(acc[3] * inv) << 16);
    pk.z = (unsigned)f2bf(acc[4] * inv) | ((unsigned)f2bf(acc[5] * inv) << 16);
    pk.w = (unsigned)f2bf(acc[6] * inv) | ((unsigned)f2bf(acc[7] * inv) << 16);
    *(uint4*)(meanb + (size_t)node * D + l * 8) = pk;
}

// ---------------------------------------------------------------------------
// 6) MFMA GEMM: out = meanb @ W + xb @ Wr + bias.
//    512 thr (8 waves), 256 rows/block; Wtb staged in 64 KiB LDS (shared by
//    8 waves, conflict-free ds_read_b128). 2 blocks/CU -> 16 waves/CU.
//    Plain stores (L2-coalesced; NT stores regressed in R12).
// ---------------------------------------------------------------------------
__global__ __launch_bounds__(512, 4) void gemm_kernel(
    const unsigned short* __restrict__ meanb,
    const unsigned short* __restrict__ xb,
    const unsigned short* __restrict__ Wtb,
    const float* __restrict__ bias,
    float* __restrict__ out)
{
    __shared__ unsigned short Bs[4096 * 8];      // 64 KiB

    const int t = threadIdx.x;
    {
        const uint4* src = (const uint4*)Wtb;
        uint4* dst = (uint4*)Bs;
#pragma unroll
        for (int i = 0; i < 8; ++i) dst[t + i * 512] = src[t + i * 512];
    }

    const int wave = t >> 6;
    const int lane = t & 63;
    const int base = blockIdx.x * 256;
    const int rL0 = wave * 32 + (lane & 15);
    const int rL1 = rL0 + 16;
    const int kO = (lane >> 4) * 8;

    int g0 = base + rL0; if (g0 > N_NODES - 1) g0 = N_NODES - 1;
    int g1 = base + rL1; if (g1 > N_NODES - 1) g1 = N_NODES - 1;
    const unsigned short* mr0 = meanb + (size_t)g0 * D + kO;
    const unsigned short* mr1 = meanb + (size_t)g1 * D + kO;
    const unsigned short* xr0 = xb + (size_t)g0 * D + kO;
    const unsigned short* xr1 = xb + (size_t)g1 * D + kO;

    f32x4 acc0[8], acc1[8];
#pragma unroll
    for (int ct = 0; ct < 8; ++ct) {
        const float bv = bias[ct * 16 + (lane & 15)];
        f32x4 b4 = {bv, bv, bv, bv};
        acc0[ct] = b4;
        acc1[ct] = b4;
    }
    __syncthreads();

    const bf16x8* __restrict__ Bp = (const bf16x8*)Bs;
#pragma unroll
    for (int ks = 0; ks < 4; ++ks) {
        bf16x8 am0 = *(const bf16x8*)(mr0 + ks * 32);
        bf16x8 am1 = *(const bf16x8*)(mr1 + ks * 32);
        bf16x8 ax0 = *(const bf16x8*)(xr0 + ks * 32);
        bf16x8 ax1 = *(const bf16x8*)(xr1 + ks * 32);
#pragma unroll
        for (int ct = 0; ct < 8; ++ct) {
            bf16x8 bm = Bp[(ct * 8 + ks) * 64 + lane];
            bf16x8 bx = Bp[(ct * 8 + 4 + ks) * 64 + lane];
            acc0[ct] = __builtin_amdgcn_mfma_f32_16x16x32_bf16(am0, bm, acc0[ct], 0, 0, 0);
            acc1[ct] = __builtin_amdgcn_mfma_f32_16x16x32_bf16(am1, bm, acc1[ct], 0, 0, 0);
            acc0[ct] = __builtin_amdgcn_mfma_f32_16x16x32_bf16(ax0, bx, acc0[ct], 0, 0, 0);
            acc1[ct] = __builtin_amdgcn_mfma_f32_16x16x32_bf16(ax1, bx, acc1[ct], 0, 0, 0);
        }
    }

    // C/D layout: col = lane&15, row = (lane>>4)*4 + reg
    const int row0b = base + wave * 32 + (lane >> 4) * 4;
#pragma unroll
    for (int ct = 0; ct < 8; ++ct) {
        const int col = ct * 16 + (lane & 15);
#pragma unroll
        for (int r = 0; r < 4; ++r) {
            const int row0 = row0b + r;
            if (row0 < N_NODES) out[(size_t)row0 * D + col] = acc0[ct][r];
            const int row1 = row0 + 16;
            if (row1 < N_NODES) out[(size_t)row1 * D + col] = acc1[ct][r];
        }
    }
}

extern "C" void kernel_launch(void* const* d_in, const int* in_sizes, int n_in,
                              void* d_out, int out_size, void* d_ws, size_t ws_size,
                              hipStream_t stream) {
    const float* x           = (const float*)d_in[0];
    const float* weight      = (const float*)d_in[1];
    const float* root_weight = (const float*)d_in[2];
    const float* bias        = (const float*)d_in[3];
    const int* edge_src      = (const int*)d_in[4];
    const int* edge_dst      = (const int*)d_in[5];
    float* out = (float*)d_out;

    // ws layout:
    //   xb       bf16[N][128]        25,600,000 B
    //   meanb    bf16[N][128]        25,600,000 B
    //   Wtb      bf16[4096*8]            65,536 B
    //   A        int[100001]  (deg -> row_start in-place)
    //   rank     int[640000]
    //   partials int[128]
    //   csr      int[640000]
    char* wsb = (char*)d_ws;
    unsigned short* xb    = (unsigned short*)wsb;
    unsigned short* meanb = (unsigned short*)(wsb + 25600000);
    unsigned short* Wtb   = (unsigned short*)(wsb + 51200000);
    int* A        = (int*)(wsb + 51265536);
    int* rank     = A + SCAN_N;
    int* partials = rank + N_EDGES;
    int* csr      = partials + 128;

    convert_kernel<<<CONV_BLKS, 256, 0, stream>>>(x, xb, A);
    degrank_kernel<<<DEGRANK_BLKS, 256, 0, stream>>>(
        edge_dst, weight, root_weight, A, rank, Wtb);
    scan_part_kernel<<<SCAN_B, 1024, 0, stream>>>(A, partials);
    scan_apply_kernel<<<SCAN_B, 1024, 0, stream>>>(A, partials);
    fill_kernel<<<FILL_BLKS, 256, 0, stream>>>(
        edge_src, edge_dst, A, rank, csr);

    gather_kernel<<<N_NODES / 16, 256, 0, stream>>>(xb, A, csr, meanb);

    const int gemm_blocks = (N_NODES + 255) / 256;   // 391
    gemm_kernel<<<gemm_blocks, 512, 0, stream>>>(meanb, xb, Wtb, bias, out);
}

// Round 14
// 108.833 us; speedup vs baseline: 1.0537x; 1.0150x over previous
//
#include <hip/hip_runtime.h>
#include <cstddef>

#define N_NODES 100000
#define N_EDGES 640000
#define D 128

#define SCAN_N (N_NODES + 1)                 // 100001
#define SCAN_B ((SCAN_N + 1023) / 1024)      // 98

// convert: 3.2M float4 chunks = 2500 blocks * 256 thr * 5 chunks (exact)
#define CONV_BLKS 2500
#define T_CONV (CONV_BLKS * 256)             // 640000

// degrank: 640000 edges = 625 blocks * 256 thr * 4 edges (exact); +16 pack blocks
#define DEG_BLKS 625
#define T_DEG (DEG_BLKS * 256)               // 160000
#define DEGRANK_BLKS (DEG_BLKS + 16)

#define FILL_BLKS 1250
#define T_FILL (FILL_BLKS * 256)             // 320000 (2 edges/thread)

typedef __attribute__((ext_vector_type(4))) float f32x4;
typedef __attribute__((ext_vector_type(8))) short bf16x8;

__device__ __forceinline__ unsigned short f2bf(float f) {
    union { float f; unsigned int u; } v; v.f = f;
    unsigned int u = v.u;
    return (unsigned short)((u + 0x7FFFu + ((u >> 16) & 1u)) >> 16);   // RNE
}
__device__ __forceinline__ float bf2f(unsigned short u) {
    union { unsigned int u; float f; } v; v.u = ((unsigned int)u) << 16;
    return v.f;
}

// ---------------------------------------------------------------------------
// 1) convert: x (fp32) -> xb (bf16), 5 strided chunks/thread, lane-contiguous.
//    Also zeroes A[0..SCAN_N) and the 128 scan flags (graph-replay safe:
//    re-zeroed every call before any use).
// ---------------------------------------------------------------------------
__global__ __launch_bounds__(256) void convert_kernel(
    const float* __restrict__ x, unsigned short* __restrict__ xb,
    int* __restrict__ A, int* __restrict__ flags)
{
    const int tid = blockIdx.x * 256 + threadIdx.x;
    if (tid < SCAN_N) A[tid] = 0;                 // coalesced; runs before degrank
    if (tid < 128) flags[tid] = 0;                // scan lookback flags
#pragma unroll
    for (int k = 0; k < 5; ++k) {
        const size_t c = (size_t)tid + (size_t)k * T_CONV;
        f32x4 v = *(const f32x4*)(x + c * 4);
        uint2 p;
        p.x = (unsigned)f2bf(v[0]) | ((unsigned)f2bf(v[1]) << 16);
        p.y = (unsigned)f2bf(v[2]) | ((unsigned)f2bf(v[3]) << 16);
        *(uint2*)(xb + c * 4) = p;
    }
}

// ---------------------------------------------------------------------------
// 2) degrank: blocks [0,625): deg count + rank capture, 4 strided edges/thr;
//             blocks [625,641): weight pack into MFMA B-fragment order.
//    Wtb fragment f=(ct*8+ks)*64+lane holds 8 bf16:
//    B[k=ks*32+(lane>>4)*8+j][n=ct*16+(lane&15)], k<128 -> W, else Wr.
// ---------------------------------------------------------------------------
__global__ __launch_bounds__(256) void degrank_kernel(
    const int* __restrict__ edge_dst,
    const float* __restrict__ W, const float* __restrict__ Wr,
    int* __restrict__ A, int* __restrict__ rank,
    unsigned short* __restrict__ Wtb)
{
    const int b = blockIdx.x;
    const int t = threadIdx.x;
    if (b < DEG_BLKS) {
        const int tid = b * 256 + t;
        const int e0 = tid;
        const int e1 = tid + T_DEG;
        const int e2 = tid + 2 * T_DEG;
        const int e3 = tid + 3 * T_DEG;
        const int d0 = edge_dst[e0];
        const int d1 = edge_dst[e1];
        const int d2 = edge_dst[e2];
        const int d3 = edge_dst[e3];
        const int r0 = atomicAdd(&A[d0], 1);
        const int r1 = atomicAdd(&A[d1], 1);
        const int r2 = atomicAdd(&A[d2], 1);
        const int r3 = atomicAdd(&A[d3], 1);
        rank[e0] = r0;
        rank[e1] = r1;
        rank[e2] = r2;
        rank[e3] = r3;
    } else {
        const int f = (b - DEG_BLKS) * 256 + t;   // 0..4095
        const int l  = f & 63;
        const int ks = (f >> 6) & 7;
        const int ct = f >> 9;
        const int n  = ct * 16 + (l & 15);
        const int kb = ks * 32 + (l >> 4) * 8;
        unsigned short vals[8];
#pragma unroll
        for (int j = 0; j < 8; ++j) {
            const int k = kb + j;
            const float w = (k < 128) ? W[k * 128 + n] : Wr[(k - 128) * 128 + n];
            vals[j] = f2bf(w);
        }
        uint4 pk;
        pk.x = (unsigned)vals[0] | ((unsigned)vals[1] << 16);
        pk.y = (unsigned)vals[2] | ((unsigned)vals[3] << 16);
        pk.z = (unsigned)vals[4] | ((unsigned)vals[5] << 16);
        pk.w = (unsigned)vals[6] | ((unsigned)vals[7] << 16);
        ((uint4*)Wtb)[f] = pk;
    }
}

// ---------------------------------------------------------------------------
// 3) Single-kernel in-place exclusive scan of A[0..SCAN_N), parallel lookback.
//    98 blocks, all co-resident on 256 CUs -> no deadlock. Block b publishes
//    total+1 via device-scope atomicExch; threads t<b spin on flags[t] in
//    parallel, then tree-reduce the prefix. (Correctness proven in R12.)
// ---------------------------------------------------------------------------
__global__ __launch_bounds__(1024) void scan_kernel(
    int* __restrict__ A, int* __restrict__ flags)
{
    __shared__ int sums[1024];
    __shared__ int red[1024];
    const int t = threadIdx.x;
    const int b = blockIdx.x;
    const int gid = b * 1024 + t;
    const int v = (gid < SCAN_N) ? A[gid] : 0;
    sums[t] = v;
    __syncthreads();
    for (int off = 1; off < 1024; off <<= 1) {       // inclusive scan in LDS
        int u = (t >= off) ? sums[t - off] : 0;
        __syncthreads();
        sums[t] += u;
        __syncthreads();
    }
    if (t == 0) atomicExch(&flags[b], sums[1023] + 1);   // publish block total

    int contrib = 0;
    if (t < b) {                                     // parallel lookback
        int f;
        do { f = atomicAdd(&flags[t], 0); } while (f == 0);
        contrib = f - 1;
    }
    red[t] = contrib;
    __syncthreads();
    for (int s = 512; s > 0; s >>= 1) {
        if (t < s) red[t] += red[t + s];
        __syncthreads();
    }
    const int excl = red[0] + sums[t] - v;
    if (gid < SCAN_N) A[gid] = excl;
}

// ---------------------------------------------------------------------------
// 4) Fill CSR: atomic-free (pos = row_start + precomputed rank), 2 edges/thr.
// ---------------------------------------------------------------------------
__global__ __launch_bounds__(256) void fill_kernel(
    const int* __restrict__ edge_src, const int* __restrict__ edge_dst,
    const int* __restrict__ A /*row_start*/, const int* __restrict__ rank,
    int* __restrict__ csr)
{
    const int tid = blockIdx.x * 256 + threadIdx.x;
    const int e0 = tid;
    const int e1 = tid + T_FILL;
    const int d0 = edge_dst[e0];
    const int d1 = edge_dst[e1];
    const int s0 = edge_src[e0];
    const int s1 = edge_src[e1];
    const int r0 = rank[e0];
    const int r1 = rank[e1];
    csr[A[d0] + r0] = s0;
    csr[A[d1] + r1] = s1;
}

// ---------------------------------------------------------------------------
// 5) Gather-mean: quarter-wave (16 lanes x 16B) per node, fp32 register
//    accumulate over bf16 rows, unroll 4/2/1; write mean row as bf16.
//    (R13's 8-deep variant measured neutral -> gather is at its random-read
//    fabric floor; keeping the R11 best-measured form.)
// ---------------------------------------------------------------------------
__global__ __launch_bounds__(256) void gather_kernel(
    const unsigned short* __restrict__ xb, const int* __restrict__ A,
    const int* __restrict__ csr, unsigned short* __restrict__ meanb)
{
    const int t = threadIdx.x;
    const int node = blockIdx.x * 16 + (t >> 4);
    const int l = t & 15;                        // owns dims 8l..8l+7
    const int rs = A[node], re = A[node + 1];
    float acc[8] = {0.f, 0.f, 0.f, 0.f, 0.f, 0.f, 0.f, 0.f};
    const unsigned short* xp = xb + (size_t)l * 8;
    int e = rs;
    for (; e + 3 < re; e += 4) {
        const int s0 = csr[e], s1 = csr[e + 1], s2 = csr[e + 2], s3 = csr[e + 3];
        bf16x8 v0 = *(const bf16x8*)(xp + (size_t)s0 * D);
        bf16x8 v1 = *(const bf16x8*)(xp + (size_t)s1 * D);
        bf16x8 v2 = *(const bf16x8*)(xp + (size_t)s2 * D);
        bf16x8 v3 = *(const bf16x8*)(xp + (size_t)s3 * D);
#pragma unroll
        for (int j = 0; j < 8; ++j)
            acc[j] += (bf2f((unsigned short)v0[j]) + bf2f((unsigned short)v1[j]))
                    + (bf2f((unsigned short)v2[j]) + bf2f((unsigned short)v3[j]));
    }
    if (e + 1 < re) {
        const int s0 = csr[e], s1 = csr[e + 1];
        bf16x8 v0 = *(const bf16x8*)(xp + (size_t)s0 * D);
        bf16x8 v1 = *(const bf16x8*)(xp + (size_t)s1 * D);
#pragma unroll
        for (int j = 0; j < 8; ++j)
            acc[j] += bf2f((unsigned short)v0[j]) + bf2f((unsigned short)v1[j]);
        e += 2;
    }
    if (e < re) {
        const int s = csr[e];
        bf16x8 v = *(const bf16x8*)(xp + (size_t)s * D);
#pragma unroll
        for (int j = 0; j < 8; ++j) acc[j] += bf2f((unsigned short)v[j]);
    }
    const float inv = 1.0f / fmaxf((float)(re - rs), 1.0f);
    uint4 pk;
    pk.x = (unsigned)f2bf(acc[0] * inv) | ((unsigned)f2bf(acc[1] * inv) << 16);
    pk.y = (unsigned)f2bf(acc[2] * inv) | ((unsigned)f2bf(acc[3] * inv) << 16);
    pk.z = (unsigned)f2bf(acc[4] * inv) | ((unsigned)f2bf(acc[5] * inv) << 16);
    pk.w = (unsigned)f2bf(acc[6] * inv) | ((unsigned)f2bf(acc[7] * inv) << 16);
    *(uint4*)(meanb + (size_t)node * D + l * 8) = pk;
}

// ---------------------------------------------------------------------------
// 6) MFMA GEMM: out = meanb @ W + xb @ Wr + bias.
//    512 thr (8 waves), 256 rows/block; Wtb staged in 64 KiB LDS (shared by
//    8 waves, conflict-free ds_read_b128). 2 blocks/CU -> 16 waves/CU.
// ---------------------------------------------------------------------------
__global__ __launch_bounds__(512, 4) void gemm_kernel(
    const unsigned short* __restrict__ meanb,
    const unsigned short* __restrict__ xb,
    const unsigned short* __restrict__ Wtb,
    const float* __restrict__ bias,
    float* __restrict__ out)
{
    __shared__ unsigned short Bs[4096 * 8];      // 64 KiB

    const int t = threadIdx.x;
    {
        const uint4* src = (const uint4*)Wtb;
        uint4* dst = (uint4*)Bs;
#pragma unroll
        for (int i = 0; i < 8; ++i) dst[t + i * 512] = src[t + i * 512];
    }

    const int wave = t >> 6;
    const int lane = t & 63;
    const int base = blockIdx.x * 256;
    const int rL0 = wave * 32 + (lane & 15);
    const int rL1 = rL0 + 16;
    const int kO = (lane >> 4) * 8;

    int g0 = base + rL0; if (g0 > N_NODES - 1) g0 = N_NODES - 1;
    int g1 = base + rL1; if (g1 > N_NODES - 1) g1 = N_NODES - 1;
    const unsigned short* mr0 = meanb + (size_t)g0 * D + kO;
    const unsigned short* mr1 = meanb + (size_t)g1 * D + kO;
    const unsigned short* xr0 = xb + (size_t)g0 * D + kO;
    const unsigned short* xr1 = xb + (size_t)g1 * D + kO;

    f32x4 acc0[8], acc1[8];
#pragma unroll
    for (int ct = 0; ct < 8; ++ct) {
        const float bv = bias[ct * 16 + (lane & 15)];
        f32x4 b4 = {bv, bv, bv, bv};
        acc0[ct] = b4;
        acc1[ct] = b4;
    }
    __syncthreads();

    const bf16x8* __restrict__ Bp = (const bf16x8*)Bs;
#pragma unroll
    for (int ks = 0; ks < 4; ++ks) {
        bf16x8 am0 = *(const bf16x8*)(mr0 + ks * 32);
        bf16x8 am1 = *(const bf16x8*)(mr1 + ks * 32);
        bf16x8 ax0 = *(const bf16x8*)(xr0 + ks * 32);
        bf16x8 ax1 = *(const bf16x8*)(xr1 + ks * 32);
#pragma unroll
        for (int ct = 0; ct < 8; ++ct) {
            bf16x8 bm = Bp[(ct * 8 + ks) * 64 + lane];
            bf16x8 bx = Bp[(ct * 8 + 4 + ks) * 64 + lane];
            acc0[ct] = __builtin_amdgcn_mfma_f32_16x16x32_bf16(am0, bm, acc0[ct], 0, 0, 0);
            acc1[ct] = __builtin_amdgcn_mfma_f32_16x16x32_bf16(am1, bm, acc1[ct], 0, 0, 0);
            acc0[ct] = __builtin_amdgcn_mfma_f32_16x16x32_bf16(ax0, bx, acc0[ct], 0, 0, 0);
            acc1[ct] = __builtin_amdgcn_mfma_f32_16x16x32_bf16(ax1, bx, acc1[ct], 0, 0, 0);
        }
    }

    // C/D layout: col = lane&15, row = (lane>>4)*4 + reg
    const int row0b = base + wave * 32 + (lane >> 4) * 4;
#pragma unroll
    for (int ct = 0; ct < 8; ++ct) {
        const int col = ct * 16 + (lane & 15);
#pragma unroll
        for (int r = 0; r < 4; ++r) {
            const int row0 = row0b + r;
            if (row0 < N_NODES) out[(size_t)row0 * D + col] = acc0[ct][r];
            const int row1 = row0 + 16;
            if (row1 < N_NODES) out[(size_t)row1 * D + col] = acc1[ct][r];
        }
    }
}

extern "C" void kernel_launch(void* const* d_in, const int* in_sizes, int n_in,
                              void* d_out, int out_size, void* d_ws, size_t ws_size,
                              hipStream_t stream) {
    const float* x           = (const float*)d_in[0];
    const float* weight      = (const float*)d_in[1];
    const float* root_weight = (const float*)d_in[2];
    const float* bias        = (const float*)d_in[3];
    const int* edge_src      = (const int*)d_in[4];
    const int* edge_dst      = (const int*)d_in[5];
    float* out = (float*)d_out;

    // ws layout:
    //   xb       bf16[N][128]        25,600,000 B
    //   meanb    bf16[N][128]        25,600,000 B
    //   Wtb      bf16[4096*8]            65,536 B
    //   A        int[100001]  (deg -> row_start in-place)
    //   rank     int[640000]
    //   flags    int[128]     (scan lookback; zeroed by convert each call)
    //   csr      int[640000]
    char* wsb = (char*)d_ws;
    unsigned short* xb    = (unsigned short*)wsb;
    unsigned short* meanb = (unsigned short*)(wsb + 25600000);
    unsigned short* Wtb   = (unsigned short*)(wsb + 51200000);
    int* A     = (int*)(wsb + 51265536);
    int* rank  = A + SCAN_N;
    int* flags = rank + N_EDGES;
    int* csr   = flags + 128;

    convert_kernel<<<CONV_BLKS, 256, 0, stream>>>(x, xb, A, flags);
    degrank_kernel<<<DEGRANK_BLKS, 256, 0, stream>>>(
        edge_dst, weight, root_weight, A, rank, Wtb);
    scan_kernel<<<SCAN_B, 1024, 0, stream>>>(A, flags);
    fill_kernel<<<FILL_BLKS, 256, 0, stream>>>(
        edge_src, edge_dst, A, rank, csr);

    gather_kernel<<<N_NODES / 16, 256, 0, stream>>>(xb, A, csr, meanb);

    const int gemm_blocks = (N_NODES + 255) / 256;   // 391
    gemm_kernel<<<gemm_blocks, 512, 0, stream>>>(meanb, xb, Wtb, bias, out);
}